// Round 7
// baseline (455.259 us; speedup 1.0000x reference)
//
#include <hip/hip_runtime.h>
#include <hip/hip_bf16.h>
#include <math.h>

#define B_    4
#define CIN_  64
#define COUT_ 64
#define DD    8
#define HH    48
#define WW    48
#define HW2   (HH * WW)        // 2304
#define NN    (DD * HH * WW)   // 18432
#define BN    (B_ * NN)        // 73728
#define KK    27
#define OCT   108

typedef float f32x2 __attribute__((ext_vector_type(2)));
typedef float f32x4 __attribute__((ext_vector_type(4)));
typedef unsigned int u32x4 __attribute__((ext_vector_type(4)));
typedef __bf16 bf16x8 __attribute__((ext_vector_type(8)));
typedef __hip_bfloat16 bf16_t;

__device__ __forceinline__ float bflo(unsigned int u) {
  return __uint_as_float(u << 16);
}
__device__ __forceinline__ float bfhi(unsigned int u) {
  return __uint_as_float(u & 0xffff0000u);
}

// ---------------------------------------------------------------------------
__global__ void zp_init_kernel(bf16_t* __restrict__ zp)
{
  zp[threadIdx.x] = __float2bfloat16(0.f);
}

// ---------------------------------------------------------------------------
// Transpose x[b][c][n] -> xTbf[b][n][c] in bf16.
// ---------------------------------------------------------------------------
__global__ __launch_bounds__(256) void transpose_x_kernel(
    const float* __restrict__ x, bf16_t* __restrict__ xTbf)
{
  const int tid = threadIdx.x;
  const int n0  = blockIdx.x * 64;
  const int b   = blockIdx.y;
  __shared__ float tile[64][65];

  for (int i = tid; i < 4096; i += 256) {
    const int c  = i >> 6;
    const int nl = i & 63;
    tile[c][nl] = x[((size_t)(b * CIN_ + c)) * NN + n0 + nl];
  }
  __syncthreads();
  for (int i = tid; i < 4096; i += 256) {
    const int nl = i >> 6;
    const int c  = i & 63;
    xTbf[((size_t)(b * NN + n0 + nl)) * CIN_ + c] = __float2bfloat16(tile[c][nl]);
  }
}

// ---------------------------------------------------------------------------
// Conv weights wB[k][ch(112 pad)][cin] bf16 (offset+mask fused).
// ---------------------------------------------------------------------------
__global__ __launch_bounds__(256) void wb_build_kernel(
    const float* __restrict__ w_off, const float* __restrict__ w_mask,
    bf16_t* __restrict__ wB)
{
  const int o  = blockIdx.x * 256 + threadIdx.x;   // 27*112*64
  const int ci = o & 63;
  const int ch = (o >> 6) % 112;
  const int k  = o / (112 * 64);
  float v = 0.f;
  if (ch < 81)       v = w_off[((size_t)ch * CIN_ + ci) * KK + k];
  else if (ch < 108) v = w_mask[((size_t)(ch - 81) * CIN_ + ci) * KK + k];
  wB[o] = __float2bfloat16(v);
}

// ---------------------------------------------------------------------------
// Deform weights wBd[k][cout][cin] bf16.
// ---------------------------------------------------------------------------
__global__ __launch_bounds__(256) void wbd_build_kernel(
    const float* __restrict__ weight, bf16_t* __restrict__ wBd)
{
  const int o  = blockIdx.x * 256 + threadIdx.x;   // 110592
  const int ci = o & 63;
  const int co = (o >> 6) & 63;
  const int k  = o >> 12;
  wBd[o] = __float2bfloat16(weight[((size_t)co * CIN_ + ci) * KK + k]);
}

// ---------------------------------------------------------------------------
// Kernel 1: fused 108-ch 3x3x3 conv via MFMA, POSITION-split.
// One wave = 16 positions x 112 channels (single M fragment, NF=7).
// 4608 waves total (grid 1152 x 4 waves) -> 18 waves/CU.
// B-tiles identical across waves (L1/L2 broadcast); A-gathers not duplicated.
// Output layout (k-major): convO[k][b*NN+n][4] = {oz,oy,ox,mask-logit} fp32.
// ---------------------------------------------------------------------------
__global__ __launch_bounds__(256) void conv108_mfma_kernel(
    const bf16_t* __restrict__ xTbf, const bf16_t* __restrict__ wB,
    const float* __restrict__ b_off, const float* __restrict__ b_mask,
    const bf16_t* __restrict__ zp, float* __restrict__ convO)
{
  const int bid  = (blockIdx.x % 8) * 144 + blockIdx.x / 8;  // XCD swizzle (1152=8*144)
  const int tid  = threadIdx.x;
  const int wave = tid >> 6;
  const int lane = tid & 63;
  const int lg   = lane >> 4;
  const int lr   = lane & 15;

  const int gw = bid * 4 + wave;              // 0..4607
  const int b  = gw / 1152;
  const int n0 = (gw % 1152) * 16;

  const int n   = n0 + lr;
  const int zj  = n / HW2;
  const int rm  = n - zj * HW2;
  const int yj  = rm / WW;
  const int xj  = rm - yj * WW;

  f32x4 acc[7];
#pragma unroll
  for (int nf = 0; nf < 7; ++nf) acc[nf] = (f32x4){0.f, 0.f, 0.f, 0.f};

#pragma unroll 3
  for (int k = 0; k < KK; ++k) {
    const int kz = k / 9;
    const int kr = k - kz * 9;
    const int ky = kr / 3;
    const int kx = kr - ky * 3;

    const int zz = zj + kz - 1;
    const int yy = yj + ky - 1;
    const int xx = xj + kx - 1;
    const bool v = ((unsigned)zz < (unsigned)DD) &
                   ((unsigned)yy < (unsigned)HH) &
                   ((unsigned)xx < (unsigned)WW);
    const bf16_t* ab =
        v ? (xTbf + ((size_t)b * NN + (zz * HH + yy) * WW + xx) * CIN_) : zp;

    bf16x8 afr[2];
#pragma unroll
    for (int t = 0; t < 2; ++t)
      afr[t] = *(const bf16x8*)(ab + 32 * t + 8 * lg);

    const bf16_t* wk = wB + (size_t)k * (112 * 64) + lr * 64 + 8 * lg;
#pragma unroll
    for (int nf = 0; nf < 7; ++nf) {
      const bf16x8 b0 = *(const bf16x8*)(wk + nf * 1024);
      const bf16x8 b1 = *(const bf16x8*)(wk + nf * 1024 + 32);
      acc[nf] = __builtin_amdgcn_mfma_f32_16x16x32_bf16(afr[0], b0, acc[nf], 0, 0, 0);
      acc[nf] = __builtin_amdgcn_mfma_f32_16x16x32_bf16(afr[1], b1, acc[nf], 0, 0, 0);
    }
  }

  // epilogue: bias + store into k-major [k][bn][4] layout.
  // C/D: row(pos) = 4*lg + r, col(ch) = 16*nf + lr
#pragma unroll
  for (int nf = 0; nf < 7; ++nf) {
    const int ch = 16 * nf + lr;
    if (ch < 108) {
      const float bv = (ch < 81) ? b_off[ch] : b_mask[ch - 81];
      const int   kI = (ch < 81) ? (ch / 3) : (ch - 81);
      const int   d  = (ch < 81) ? (ch % 3) : 3;
#pragma unroll
      for (int r = 0; r < 4; ++r) {
        const int row = n0 + 4 * lg + r;
        convO[((size_t)kI * BN + (size_t)b * NN + row) * 4 + d] = acc[nf][r] + bv;
      }
    }
  }
}

// ---------------------------------------------------------------------------
// Kernel 2: softmax over K=27 mask logits at convO[k][i][3], in place.
// ---------------------------------------------------------------------------
__global__ __launch_bounds__(256) void softmaxT_kernel(float* __restrict__ convO)
{
  const int i = blockIdx.x * 256 + threadIdx.x;   // BN exact
  float* p = convO + (size_t)i * 4 + 3;

  float v[KK];
  float mx = -1e30f;
#pragma unroll
  for (int k = 0; k < KK; ++k) { v[k] = p[(size_t)k * BN * 4]; mx = fmaxf(mx, v[k]); }
  float s = 0.f;
#pragma unroll
  for (int k = 0; k < KK; ++k) { v[k] = expf(v[k] - mx); s += v[k]; }
  const float inv = 1.f / s;
#pragma unroll
  for (int k = 0; k < KK; ++k) p[(size_t)k * BN * 4] = v[k] * inv;
}

// ---------------------------------------------------------------------------
// Kernel 3: deformable gather (octet scheme) + MFMA tap-GEMM,
// split-K 2-way (grid.y: taps 0..13 -> out, 14..26 -> p1), tap loop
// unrolled 2-deep so next tap's om-load/gather issues under current MFMA.
// ---------------------------------------------------------------------------
__global__ __launch_bounds__(256) void deform_mfma_kernel(
    const bf16_t* __restrict__ xTbf, const float* __restrict__ convO,
    const bf16_t* __restrict__ wBd, float* __restrict__ out0,
    float* __restrict__ p1)
{
  const int bid  = (blockIdx.x % 8) * 72 + blockIdx.x / 8;   // XCD swizzle
  const int g    = blockIdx.y;
  const int k0   = g ? 14 : 0;
  const int kN   = g ? 13 : 14;
  float* target  = g ? p1 : out0;

  const int tid  = threadIdx.x;
  const int wid  = tid >> 6;
  const int lane = tid & 63;
  const int p8   = lane >> 3;     // position within octet
  const int q    = lane & 7;      // channel octet
  const int lr   = lane & 15;     // MFMA row/col
  const int lg   = lane >> 4;

  const int tile = bid * 4 + wid;           // 0..2303
  const int b    = tile / 576;
  const int rem  = tile % 576;
  const int z    = rem / 72;
  const int r2   = rem % 72;
  const int y0   = (r2 / 3) * 2;
  const int x0   = (r2 % 3) * 16;
  const int n0   = (z * HH + y0) * WW + x0;
  const size_t n0g = (size_t)b * NN + n0;

  const unsigned short* xq =
      (const unsigned short*)(xTbf + (size_t)b * NN * CIN_) + (q << 3);

  __shared__ __align__(16) unsigned short S[4][32][64];
  unsigned short* Sw  = &S[wid][0][0];
  unsigned int*   SwU = (unsigned int*)Sw;

  // per-lane constants for the 4 octets
  int   pOff[4];
  float pxb[4], pyb[4];
#pragma unroll
  for (int oct = 0; oct < 4; ++oct) {
    const int j  = oct * 8 + p8;
    const int jy = j >> 4;
    const int jx = j & 15;
    pOff[oct] = jy * WW + jx;                 // position offset in n
    pyb[oct]  = (float)(y0 + jy - 1);
    pxb[oct]  = (float)(x0 + jx - 1);
  }
  const float pzb = (float)(z - 1);

  f32x4 acc[2][4];
#pragma unroll
  for (int mf = 0; mf < 2; ++mf)
#pragma unroll
    for (int nf = 0; nf < 4; ++nf) acc[mf][nf] = (f32x4){0.f, 0.f, 0.f, 0.f};

#pragma unroll 2
  for (int t = 0; t < kN; ++t) {
    const int k  = k0 + t;
    const int kz = k / 9;
    const int kr = k - kz * 9;
    const int ky = kr / 3;
    const int kx = kr - ky * 3;
    const float kzf = (float)kz, kyf = (float)ky, kxf = (float)kx;

    const float* cbk = convO + ((size_t)k * BN + n0g) * 4;

    // ---- Phase A: gather 8 positions x 64 channels per octet ----
#pragma unroll
    for (int oct = 0; oct < 4; ++oct) {
      const int j = oct * 8 + p8;
      const f32x4 om = *(const f32x4*)(cbk + (size_t)pOff[oct] * 4);

      const float pz = pzb + kzf + om.x;
      const float py = pyb[oct] + kyf + om.y;
      const float px = pxb[oct] + kxf + om.z;
      const float m  = om.w;

      const float zf = floorf(pz); const float fz = pz - zf; const int z0 = (int)zf;
      const float yf = floorf(py); const float fy = py - yf; const int y0i = (int)yf;
      const float xf = floorf(px); const float fx = px - xf; const int xi0 = (int)xf;

      const float wz0 = ((unsigned)z0        < DD) ? (1.f - fz) : 0.f;
      const float wz1 = ((unsigned)(z0 + 1)  < DD) ? fz         : 0.f;
      const float wy0 = ((unsigned)y0i       < HH) ? (1.f - fy) : 0.f;
      const float wy1 = ((unsigned)(y0i + 1) < HH) ? fy         : 0.f;
      const float wx0 = ((unsigned)xi0       < WW) ? (1.f - fx) : 0.f;
      const float wx1 = ((unsigned)(xi0 + 1) < WW) ? fx         : 0.f;

      const int z0c = min(max(z0, 0),      DD - 1);
      const int z1c = min(max(z0 + 1, 0),  DD - 1);
      const int y0c = min(max(y0i, 0),     HH - 1);
      const int y1c = min(max(y0i + 1, 0), HH - 1);
      const int x0c = min(max(xi0, 0),     WW - 1);
      const int x1c = min(max(xi0 + 1, 0), WW - 1);

      const int r00 = (z0c * HH + y0c) * WW;
      const int r01 = (z0c * HH + y1c) * WW;
      const int r10 = (z1c * HH + y0c) * WW;
      const int r11 = (z1c * HH + y1c) * WW;
      const float w00 = wz0 * wy0, w01 = wz0 * wy1;
      const float w10 = wz1 * wy0, w11 = wz1 * wy1;

      f32x2 a01 = {0.f, 0.f}, a23 = {0.f, 0.f}, a45 = {0.f, 0.f}, a67 = {0.f, 0.f};

#define CORNER(ROW, WGT)                                            \
      {                                                             \
        const u32x4 v = *(const u32x4*)(xq + ((size_t)(ROW) << 6)); \
        const float w_ = (WGT);                                     \
        a01 += (f32x2){bflo(v.x), bfhi(v.x)} * w_;                  \
        a23 += (f32x2){bflo(v.y), bfhi(v.y)} * w_;                  \
        a45 += (f32x2){bflo(v.z), bfhi(v.z)} * w_;                  \
        a67 += (f32x2){bflo(v.w), bfhi(v.w)} * w_;                  \
      }
      CORNER(r00 + x0c, w00 * wx0)
      CORNER(r00 + x1c, w00 * wx1)
      CORNER(r01 + x0c, w01 * wx0)
      CORNER(r01 + x1c, w01 * wx1)
      CORNER(r10 + x0c, w10 * wx0)
      CORNER(r10 + x1c, w10 * wx1)
      CORNER(r11 + x0c, w11 * wx0)
      CORNER(r11 + x1c, w11 * wx1)
#undef CORNER

      a01 *= m; a23 *= m; a45 *= m; a67 *= m;
      unsigned int d0, d1, d2, d3;
      asm("v_cvt_pk_bf16_f32 %0, %1, %2" : "=v"(d0) : "v"(a01.x), "v"(a01.y));
      asm("v_cvt_pk_bf16_f32 %0, %1, %2" : "=v"(d1) : "v"(a23.x), "v"(a23.y));
      asm("v_cvt_pk_bf16_f32 %0, %1, %2" : "=v"(d2) : "v"(a45.x), "v"(a45.y));
      asm("v_cvt_pk_bf16_f32 %0, %1, %2" : "=v"(d3) : "v"(a67.x), "v"(a67.y));
      const int slot = q ^ (j & 7);               // XOR-swizzle (T2)
      *(u32x4*)(SwU + j * 32 + slot * 4) = (u32x4){d0, d1, d2, d3};
    }

    // ---- Phase B: S[32x64] * W_k[64x64] via MFMA ----
    bf16x8 afr[2][2];
#pragma unroll
    for (int mf = 0; mf < 2; ++mf)
#pragma unroll
      for (int t2 = 0; t2 < 2; ++t2) {
        const int row  = 16 * mf + lr;
        const int slot = (t2 * 4 + lg) ^ (row & 7);
        afr[mf][t2] = *(const bf16x8*)(Sw + row * 64 + slot * 8);
      }
    const bf16_t* wk = wBd + (size_t)k * 4096 + lr * 64 + 8 * lg;
#pragma unroll
    for (int nf = 0; nf < 4; ++nf) {
      const bf16x8 b0 = *(const bf16x8*)(wk + nf * 1024);
      const bf16x8 b1 = *(const bf16x8*)(wk + nf * 1024 + 32);
      acc[0][nf] = __builtin_amdgcn_mfma_f32_16x16x32_bf16(afr[0][0], b0, acc[0][nf], 0, 0, 0);
      acc[1][nf] = __builtin_amdgcn_mfma_f32_16x16x32_bf16(afr[1][0], b0, acc[1][nf], 0, 0, 0);
      acc[0][nf] = __builtin_amdgcn_mfma_f32_16x16x32_bf16(afr[0][1], b1, acc[0][nf], 0, 0, 0);
      acc[1][nf] = __builtin_amdgcn_mfma_f32_16x16x32_bf16(afr[1][1], b1, acc[1][nf], 0, 0, 0);
    }
  }

  // epilogue (no bias; added in reduce). tile-row = 16*mf+4*lg+r ->
  // jy = mf, jx = 4*lg+r ; col = cout = 16*nf+lr
#pragma unroll
  for (int nf = 0; nf < 4; ++nf) {
    float* op = target + ((size_t)(b * COUT_ + 16 * nf + lr)) * NN + n0 + 4 * lg;
#pragma unroll
    for (int mf = 0; mf < 2; ++mf)
#pragma unroll
      for (int r = 0; r < 4; ++r)
        op[mf * WW + r] = acc[mf][nf][r];
  }
}

// ---------------------------------------------------------------------------
// Kernel 4: out += p1 + bias  (f32x4 vectorized)
// ---------------------------------------------------------------------------
__global__ __launch_bounds__(256) void reduce_kernel(
    float* __restrict__ out, const float* __restrict__ p1,
    const float* __restrict__ bias)
{
  const int i = blockIdx.x * 256 + threadIdx.x;   // BN*COUT/4 exact
  const int cout = (i / (NN / 4)) & 63;
  const f32x4 a = ((const f32x4*)out)[i];
  const f32x4 c = ((const f32x4*)p1)[i];
  const float bv = bias[cout];
  ((f32x4*)out)[i] = a + c + bv;
}

// ---------------------------------------------------------------------------
extern "C" void kernel_launch(void* const* d_in, const int* in_sizes, int n_in,
                              void* d_out, int out_size, void* d_ws, size_t ws_size,
                              hipStream_t stream)
{
  const float* x      = (const float*)d_in[0];
  const float* w_off  = (const float*)d_in[1];
  const float* b_off  = (const float*)d_in[2];
  const float* w_mask = (const float*)d_in[3];
  const float* b_mask = (const float*)d_in[4];
  const float* weight = (const float*)d_in[5];
  const float* bias   = (const float*)d_in[6];
  float* out = (float*)d_out;

  // Workspace (bytes):
  //   convO : 27*BN*4 fp32    = 31,850,496
  //   xTbf  : BN*64 bf16      =  9,437,184
  //   wB    : 27*112*64 bf16  =    387,072
  //   wBd   : 27*64*64 bf16   =    221,184
  //   zp    : 256
  //   p1    : BN*64 fp32      = 18,874,368   (total ~60.8 MB)
  char* ws = (char*)d_ws;
  float*  convO = (float*)ws;
  bf16_t* xTbf  = (bf16_t*)(ws + 31850496);
  bf16_t* wB    = (bf16_t*)(ws + 31850496 + 9437184);
  bf16_t* wBd   = (bf16_t*)(ws + 31850496 + 9437184 + 387072);
  bf16_t* zp    = (bf16_t*)(ws + 31850496 + 9437184 + 387072 + 221184);
  float*  p1    = (float*)(ws + 31850496 + 9437184 + 387072 + 221184 + 256);

  zp_init_kernel<<<1, 64, 0, stream>>>(zp);
  dim3 gtx(NN / 64, B_);
  transpose_x_kernel<<<gtx, 256, 0, stream>>>(x, xTbf);
  wb_build_kernel<<<(KK * 112 * 64) / 256, 256, 0, stream>>>(w_off, w_mask, wB);
  wbd_build_kernel<<<(KK * CIN_ * COUT_) / 256, 256, 0, stream>>>(weight, wBd);

  conv108_mfma_kernel<<<1152, 256, 0, stream>>>(xTbf, wB, b_off, b_mask, zp, convO);
  softmaxT_kernel<<<BN / 256, 256, 0, stream>>>(convO);
  deform_mfma_kernel<<<dim3(576, 2), 256, 0, stream>>>(xTbf, convO, wBd, out, p1);
  reduce_kernel<<<(BN * COUT_ / 4) / 256, 256, 0, stream>>>(out, p1, bias);
}

// Round 8
// 382.723 us; speedup vs baseline: 1.1895x; 1.1895x over previous
//
#include <hip/hip_runtime.h>
#include <hip/hip_bf16.h>
#include <math.h>

#define B_    4
#define CIN_  64
#define COUT_ 64
#define DD    8
#define HH    48
#define WW    48
#define HW2   (HH * WW)        // 2304
#define NN    (DD * HH * WW)   // 18432
#define BN    (B_ * NN)        // 73728
#define KK    27
#define OCT   108

typedef float f32x2 __attribute__((ext_vector_type(2)));
typedef float f32x4 __attribute__((ext_vector_type(4)));
typedef unsigned int u32x4 __attribute__((ext_vector_type(4)));
typedef __bf16 bf16x8 __attribute__((ext_vector_type(8)));
typedef __hip_bfloat16 bf16_t;

__device__ __forceinline__ float bflo(unsigned int u) {
  return __uint_as_float(u << 16);
}
__device__ __forceinline__ float bfhi(unsigned int u) {
  return __uint_as_float(u & 0xffff0000u);
}

// ---------------------------------------------------------------------------
__global__ void zp_init_kernel(bf16_t* __restrict__ zp)
{
  zp[threadIdx.x] = __float2bfloat16(0.f);
}

// ---------------------------------------------------------------------------
// Transpose x[b][c][n] -> xTbf[b][n][c] in bf16.
// ---------------------------------------------------------------------------
__global__ __launch_bounds__(256) void transpose_x_kernel(
    const float* __restrict__ x, bf16_t* __restrict__ xTbf)
{
  const int tid = threadIdx.x;
  const int n0  = blockIdx.x * 64;
  const int b   = blockIdx.y;
  __shared__ float tile[64][65];

  for (int i = tid; i < 4096; i += 256) {
    const int c  = i >> 6;
    const int nl = i & 63;
    tile[c][nl] = x[((size_t)(b * CIN_ + c)) * NN + n0 + nl];
  }
  __syncthreads();
  for (int i = tid; i < 4096; i += 256) {
    const int nl = i >> 6;
    const int c  = i & 63;
    xTbf[((size_t)(b * NN + n0 + nl)) * CIN_ + c] = __float2bfloat16(tile[c][nl]);
  }
}

// ---------------------------------------------------------------------------
// Conv weights wB[k][ch(112 pad)][cin] bf16 (offset+mask fused).
// ---------------------------------------------------------------------------
__global__ __launch_bounds__(256) void wb_build_kernel(
    const float* __restrict__ w_off, const float* __restrict__ w_mask,
    bf16_t* __restrict__ wB)
{
  const int o  = blockIdx.x * 256 + threadIdx.x;   // 27*112*64
  const int ci = o & 63;
  const int ch = (o >> 6) % 112;
  const int k  = o / (112 * 64);
  float v = 0.f;
  if (ch < 81)       v = w_off[((size_t)ch * CIN_ + ci) * KK + k];
  else if (ch < 108) v = w_mask[((size_t)(ch - 81) * CIN_ + ci) * KK + k];
  wB[o] = __float2bfloat16(v);
}

// ---------------------------------------------------------------------------
// Deform weights wBd[k][cout][cin] bf16.
// ---------------------------------------------------------------------------
__global__ __launch_bounds__(256) void wbd_build_kernel(
    const float* __restrict__ weight, bf16_t* __restrict__ wBd)
{
  const int o  = blockIdx.x * 256 + threadIdx.x;   // 110592
  const int ci = o & 63;
  const int co = (o >> 6) & 63;
  const int k  = o >> 12;
  wBd[o] = __float2bfloat16(weight[((size_t)co * CIN_ + ci) * KK + k]);
}

// ---------------------------------------------------------------------------
// Kernel 1: fused 108-ch 3x3x3 conv via MFMA, round-4 wave structure
// (one wave = 32 positions x 112 channels), SPLIT-K over taps:
//   grid.y==0 : taps 0..13  -> convA (with bias)
//   grid.y==1 : taps 14..26 -> convB (raw)
// Output layout (k-major): conv*[k][b*NN+n][4] = {oz,oy,ox,mask-logit} fp32.
// ---------------------------------------------------------------------------
template<int K0, int K1, bool BIAS>
__device__ __forceinline__ void conv_impl(
    const bf16_t* __restrict__ xTbf, const bf16_t* __restrict__ wB,
    const float* __restrict__ b_off, const float* __restrict__ b_mask,
    const bf16_t* __restrict__ zp, float* __restrict__ target)
{
  const int bid  = (blockIdx.x % 8) * 72 + blockIdx.x / 8;  // XCD swizzle (576=8*72)
  const int tid  = threadIdx.x;
  const int wave = tid >> 6;
  const int lane = tid & 63;
  const int lg   = lane >> 4;
  const int lr   = lane & 15;

  const int gw = bid * 4 + wave;              // 0..2303
  const int b  = gw / 576;
  const int n0 = (gw % 576) * 32;

  int zj[2], yj[2], xj[2];
#pragma unroll
  for (int mf = 0; mf < 2; ++mf) {
    const int n   = n0 + 16 * mf + lr;
    const int z   = n / HW2;
    const int rem = n - z * HW2;
    const int y   = rem / WW;
    zj[mf] = z; yj[mf] = y; xj[mf] = rem - y * WW;
  }

  f32x4 acc[2][7];
#pragma unroll
  for (int mf = 0; mf < 2; ++mf)
#pragma unroll
    for (int nf = 0; nf < 7; ++nf) acc[mf][nf] = (f32x4){0.f, 0.f, 0.f, 0.f};

#pragma unroll 3
  for (int k = K0; k < K1; ++k) {
    const int kz = k / 9;
    const int kr = k - kz * 9;
    const int ky = kr / 3;
    const int kx = kr - ky * 3;

    const bf16_t* ab[2];
#pragma unroll
    for (int mf = 0; mf < 2; ++mf) {
      const int zz = zj[mf] + kz - 1;
      const int yy = yj[mf] + ky - 1;
      const int xx = xj[mf] + kx - 1;
      const bool v = ((unsigned)zz < (unsigned)DD) &
                     ((unsigned)yy < (unsigned)HH) &
                     ((unsigned)xx < (unsigned)WW);
      ab[mf] = v ? (xTbf + ((size_t)b * NN + (zz * HH + yy) * WW + xx) * CIN_)
                 : zp;
    }
    bf16x8 afr[2][2];
#pragma unroll
    for (int mf = 0; mf < 2; ++mf)
#pragma unroll
      for (int t = 0; t < 2; ++t)
        afr[mf][t] = *(const bf16x8*)(ab[mf] + 32 * t + 8 * lg);

    const bf16_t* wk = wB + (size_t)k * (112 * 64) + lr * 64 + 8 * lg;
#pragma unroll
    for (int nf = 0; nf < 7; ++nf) {
      const bf16x8 b0 = *(const bf16x8*)(wk + nf * 1024);
      const bf16x8 b1 = *(const bf16x8*)(wk + nf * 1024 + 32);
      acc[0][nf] = __builtin_amdgcn_mfma_f32_16x16x32_bf16(afr[0][0], b0, acc[0][nf], 0, 0, 0);
      acc[1][nf] = __builtin_amdgcn_mfma_f32_16x16x32_bf16(afr[1][0], b0, acc[1][nf], 0, 0, 0);
      acc[0][nf] = __builtin_amdgcn_mfma_f32_16x16x32_bf16(afr[0][1], b1, acc[0][nf], 0, 0, 0);
      acc[1][nf] = __builtin_amdgcn_mfma_f32_16x16x32_bf16(afr[1][1], b1, acc[1][nf], 0, 0, 0);
    }
  }

  // epilogue: optional bias + store into k-major [k][bn][4] layout.
  // C/D: row(pos) = 16*mf + 4*lg + r, col(ch) = 16*nf + lr
#pragma unroll
  for (int nf = 0; nf < 7; ++nf) {
    const int ch = 16 * nf + lr;
    if (ch < 108) {
      const float bv = BIAS ? ((ch < 81) ? b_off[ch] : b_mask[ch - 81]) : 0.f;
      const int   kI = (ch < 81) ? (ch / 3) : (ch - 81);
      const int   d  = (ch < 81) ? (ch % 3) : 3;
#pragma unroll
      for (int mf = 0; mf < 2; ++mf)
#pragma unroll
        for (int r = 0; r < 4; ++r) {
          const int row = n0 + 16 * mf + 4 * lg + r;
          target[((size_t)kI * BN + (size_t)b * NN + row) * 4 + d] =
              acc[mf][nf][r] + bv;
        }
    }
  }
}

__global__ __launch_bounds__(256) void conv108_mfma_kernel(
    const bf16_t* __restrict__ xTbf, const bf16_t* __restrict__ wB,
    const float* __restrict__ b_off, const float* __restrict__ b_mask,
    const bf16_t* __restrict__ zp, float* __restrict__ convA,
    float* __restrict__ convB)
{
  if (blockIdx.y == 0) conv_impl<0, 14, true >(xTbf, wB, b_off, b_mask, zp, convA);
  else                 conv_impl<14, 27, false>(xTbf, wB, b_off, b_mask, zp, convB);
}

// ---------------------------------------------------------------------------
// Kernel 2: combine partials (convA += convB) and softmax the K=27 mask
// logits, all in one coalesced pass. One thread per position.
// ---------------------------------------------------------------------------
__global__ __launch_bounds__(256) void combine_softmax_kernel(
    float* __restrict__ convA, const float* __restrict__ convB)
{
  const int i = blockIdx.x * 256 + threadIdx.x;   // BN exact
  f32x4* pa = (f32x4*)convA + i;
  const f32x4* pb = (const f32x4*)convB + i;

  float lg[KK];
  float mx = -1e30f;
#pragma unroll
  for (int k = 0; k < KK; ++k) {
    f32x4 a = pa[(size_t)k * BN];
    const f32x4 b = pb[(size_t)k * BN];
    a.x += b.x; a.y += b.y; a.z += b.z; a.w += b.w;
    pa[(size_t)k * BN] = a;          // offsets final; .w = logit (rewritten below)
    lg[k] = a.w;
    mx = fmaxf(mx, a.w);
  }
  float s = 0.f;
#pragma unroll
  for (int k = 0; k < KK; ++k) { lg[k] = expf(lg[k] - mx); s += lg[k]; }
  const float inv = 1.f / s;
#pragma unroll
  for (int k = 0; k < KK; ++k)
    convA[((size_t)k * BN + i) * 4 + 3] = lg[k] * inv;
}

// ---------------------------------------------------------------------------
// Kernel 3: deformable gather (octet scheme) + MFMA tap-GEMM,
// split-K 2-way (grid.y: taps 0..13 -> out, 14..26 -> p1). Round-6 proven.
// ---------------------------------------------------------------------------
__global__ __launch_bounds__(256) void deform_mfma_kernel(
    const bf16_t* __restrict__ xTbf, const float* __restrict__ convO,
    const bf16_t* __restrict__ wBd, float* __restrict__ out0,
    float* __restrict__ p1)
{
  const int bid  = (blockIdx.x % 8) * 72 + blockIdx.x / 8;   // XCD swizzle
  const int g    = blockIdx.y;
  const int k0   = g ? 14 : 0;
  const int kN   = g ? 13 : 14;
  float* target  = g ? p1 : out0;

  const int tid  = threadIdx.x;
  const int wid  = tid >> 6;
  const int lane = tid & 63;
  const int p8   = lane >> 3;     // position within octet
  const int q    = lane & 7;      // channel octet
  const int lr   = lane & 15;     // MFMA row/col
  const int lg   = lane >> 4;

  const int tile = bid * 4 + wid;           // 0..2303
  const int b    = tile / 576;
  const int rem  = tile % 576;
  const int z    = rem / 72;
  const int r2   = rem % 72;
  const int y0   = (r2 / 3) * 2;
  const int x0   = (r2 % 3) * 16;
  const int n0   = (z * HH + y0) * WW + x0;
  const size_t n0g = (size_t)b * NN + n0;

  const unsigned short* xq =
      (const unsigned short*)(xTbf + (size_t)b * NN * CIN_) + (q << 3);

  __shared__ __align__(16) unsigned short S[4][32][64];
  unsigned short* Sw  = &S[wid][0][0];
  unsigned int*   SwU = (unsigned int*)Sw;

  // per-lane constants for the 4 octets
  int   pOff[4];
  float pxb[4], pyb[4];
#pragma unroll
  for (int oct = 0; oct < 4; ++oct) {
    const int j  = oct * 8 + p8;
    const int jy = j >> 4;
    const int jx = j & 15;
    pOff[oct] = jy * WW + jx;                 // position offset in n
    pyb[oct]  = (float)(y0 + jy - 1);
    pxb[oct]  = (float)(x0 + jx - 1);
  }
  const float pzb = (float)(z - 1);

  f32x4 acc[2][4];
#pragma unroll
  for (int mf = 0; mf < 2; ++mf)
#pragma unroll
    for (int nf = 0; nf < 4; ++nf) acc[mf][nf] = (f32x4){0.f, 0.f, 0.f, 0.f};

#pragma unroll 2
  for (int t = 0; t < kN; ++t) {
    const int k  = k0 + t;
    const int kz = k / 9;
    const int kr = k - kz * 9;
    const int ky = kr / 3;
    const int kx = kr - ky * 3;
    const float kzf = (float)kz, kyf = (float)ky, kxf = (float)kx;

    const float* cbk = convO + ((size_t)k * BN + n0g) * 4;

    // ---- Phase A: gather 8 positions x 64 channels per octet ----
#pragma unroll
    for (int oct = 0; oct < 4; ++oct) {
      const int j = oct * 8 + p8;
      const f32x4 om = *(const f32x4*)(cbk + (size_t)pOff[oct] * 4);

      const float pz = pzb + kzf + om.x;
      const float py = pyb[oct] + kyf + om.y;
      const float px = pxb[oct] + kxf + om.z;
      const float m  = om.w;

      const float zf = floorf(pz); const float fz = pz - zf; const int z0 = (int)zf;
      const float yf = floorf(py); const float fy = py - yf; const int y0i = (int)yf;
      const float xf = floorf(px); const float fx = px - xf; const int xi0 = (int)xf;

      const float wz0 = ((unsigned)z0        < DD) ? (1.f - fz) : 0.f;
      const float wz1 = ((unsigned)(z0 + 1)  < DD) ? fz         : 0.f;
      const float wy0 = ((unsigned)y0i       < HH) ? (1.f - fy) : 0.f;
      const float wy1 = ((unsigned)(y0i + 1) < HH) ? fy         : 0.f;
      const float wx0 = ((unsigned)xi0       < WW) ? (1.f - fx) : 0.f;
      const float wx1 = ((unsigned)(xi0 + 1) < WW) ? fx         : 0.f;

      const int z0c = min(max(z0, 0),      DD - 1);
      const int z1c = min(max(z0 + 1, 0),  DD - 1);
      const int y0c = min(max(y0i, 0),     HH - 1);
      const int y1c = min(max(y0i + 1, 0), HH - 1);
      const int x0c = min(max(xi0, 0),     WW - 1);
      const int x1c = min(max(xi0 + 1, 0), WW - 1);

      const int r00 = (z0c * HH + y0c) * WW;
      const int r01 = (z0c * HH + y1c) * WW;
      const int r10 = (z1c * HH + y0c) * WW;
      const int r11 = (z1c * HH + y1c) * WW;
      const float w00 = wz0 * wy0, w01 = wz0 * wy1;
      const float w10 = wz1 * wy0, w11 = wz1 * wy1;

      f32x2 a01 = {0.f, 0.f}, a23 = {0.f, 0.f}, a45 = {0.f, 0.f}, a67 = {0.f, 0.f};

#define CORNER(ROW, WGT)                                            \
      {                                                             \
        const u32x4 v = *(const u32x4*)(xq + ((size_t)(ROW) << 6)); \
        const float w_ = (WGT);                                     \
        a01 += (f32x2){bflo(v.x), bfhi(v.x)} * w_;                  \
        a23 += (f32x2){bflo(v.y), bfhi(v.y)} * w_;                  \
        a45 += (f32x2){bflo(v.z), bfhi(v.z)} * w_;                  \
        a67 += (f32x2){bflo(v.w), bfhi(v.w)} * w_;                  \
      }
      CORNER(r00 + x0c, w00 * wx0)
      CORNER(r00 + x1c, w00 * wx1)
      CORNER(r01 + x0c, w01 * wx0)
      CORNER(r01 + x1c, w01 * wx1)
      CORNER(r10 + x0c, w10 * wx0)
      CORNER(r10 + x1c, w10 * wx1)
      CORNER(r11 + x0c, w11 * wx0)
      CORNER(r11 + x1c, w11 * wx1)
#undef CORNER

      a01 *= m; a23 *= m; a45 *= m; a67 *= m;
      unsigned int d0, d1, d2, d3;
      asm("v_cvt_pk_bf16_f32 %0, %1, %2" : "=v"(d0) : "v"(a01.x), "v"(a01.y));
      asm("v_cvt_pk_bf16_f32 %0, %1, %2" : "=v"(d1) : "v"(a23.x), "v"(a23.y));
      asm("v_cvt_pk_bf16_f32 %0, %1, %2" : "=v"(d2) : "v"(a45.x), "v"(a45.y));
      asm("v_cvt_pk_bf16_f32 %0, %1, %2" : "=v"(d3) : "v"(a67.x), "v"(a67.y));
      const int slot = q ^ (j & 7);               // XOR-swizzle (T2)
      *(u32x4*)(SwU + j * 32 + slot * 4) = (u32x4){d0, d1, d2, d3};
    }

    // ---- Phase B: S[32x64] * W_k[64x64] via MFMA ----
    bf16x8 afr[2][2];
#pragma unroll
    for (int mf = 0; mf < 2; ++mf)
#pragma unroll
      for (int t2 = 0; t2 < 2; ++t2) {
        const int row  = 16 * mf + lr;
        const int slot = (t2 * 4 + lg) ^ (row & 7);
        afr[mf][t2] = *(const bf16x8*)(Sw + row * 64 + slot * 8);
      }
    const bf16_t* wk = wBd + (size_t)k * 4096 + lr * 64 + 8 * lg;
#pragma unroll
    for (int nf = 0; nf < 4; ++nf) {
      const bf16x8 b0 = *(const bf16x8*)(wk + nf * 1024);
      const bf16x8 b1 = *(const bf16x8*)(wk + nf * 1024 + 32);
      acc[0][nf] = __builtin_amdgcn_mfma_f32_16x16x32_bf16(afr[0][0], b0, acc[0][nf], 0, 0, 0);
      acc[1][nf] = __builtin_amdgcn_mfma_f32_16x16x32_bf16(afr[1][0], b0, acc[1][nf], 0, 0, 0);
      acc[0][nf] = __builtin_amdgcn_mfma_f32_16x16x32_bf16(afr[0][1], b1, acc[0][nf], 0, 0, 0);
      acc[1][nf] = __builtin_amdgcn_mfma_f32_16x16x32_bf16(afr[1][1], b1, acc[1][nf], 0, 0, 0);
    }
  }

  // epilogue (no bias; added in reduce). tile-row = 16*mf+4*lg+r ->
  // jy = mf, jx = 4*lg+r ; col = cout = 16*nf+lr
#pragma unroll
  for (int nf = 0; nf < 4; ++nf) {
    float* op = target + ((size_t)(b * COUT_ + 16 * nf + lr)) * NN + n0 + 4 * lg;
#pragma unroll
    for (int mf = 0; mf < 2; ++mf)
#pragma unroll
      for (int r = 0; r < 4; ++r)
        op[mf * WW + r] = acc[mf][nf][r];
  }
}

// ---------------------------------------------------------------------------
// Kernel 4: out += p1 + bias  (f32x4 vectorized)
// ---------------------------------------------------------------------------
__global__ __launch_bounds__(256) void reduce_kernel(
    float* __restrict__ out, const float* __restrict__ p1,
    const float* __restrict__ bias)
{
  const int i = blockIdx.x * 256 + threadIdx.x;   // BN*COUT/4 exact
  const int cout = (i / (NN / 4)) & 63;
  const f32x4 a = ((const f32x4*)out)[i];
  const f32x4 c = ((const f32x4*)p1)[i];
  const float bv = bias[cout];
  ((f32x4*)out)[i] = a + c + bv;
}

// ---------------------------------------------------------------------------
extern "C" void kernel_launch(void* const* d_in, const int* in_sizes, int n_in,
                              void* d_out, int out_size, void* d_ws, size_t ws_size,
                              hipStream_t stream)
{
  const float* x      = (const float*)d_in[0];
  const float* w_off  = (const float*)d_in[1];
  const float* b_off  = (const float*)d_in[2];
  const float* w_mask = (const float*)d_in[3];
  const float* b_mask = (const float*)d_in[4];
  const float* weight = (const float*)d_in[5];
  const float* bias   = (const float*)d_in[6];
  float* out = (float*)d_out;

  // Workspace (bytes):
  //   convA : 27*BN*4 fp32    = 31,850,496   @ 0
  //   xTbf  : BN*64 bf16      =  9,437,184   @ 31,850,496
  //   wB    : 27*112*64 bf16  =    387,072   @ 41,287,680
  //   wBd   : 27*64*64 bf16   =    221,184   @ 41,674,752
  //   zp    : 256             @ 41,895,936
  //   convB : 27*BN*4 fp32    = 31,850,496   @ 41,896,192
  //           (p1 aliases convB: convB is dead after combine_softmax)
  // total 73,746,688 B
  char* ws = (char*)d_ws;
  float*  convA = (float*)ws;
  bf16_t* xTbf  = (bf16_t*)(ws + 31850496);
  bf16_t* wB    = (bf16_t*)(ws + 41287680);
  bf16_t* wBd   = (bf16_t*)(ws + 41674752);
  bf16_t* zp    = (bf16_t*)(ws + 41895936);
  float*  convB = (float*)(ws + 41896192);
  float*  p1    = convB;   // alias (convB dead after combine_softmax)

  zp_init_kernel<<<1, 64, 0, stream>>>(zp);
  dim3 gtx(NN / 64, B_);
  transpose_x_kernel<<<gtx, 256, 0, stream>>>(x, xTbf);
  wb_build_kernel<<<(KK * 112 * 64) / 256, 256, 0, stream>>>(w_off, w_mask, wB);
  wbd_build_kernel<<<(KK * CIN_ * COUT_) / 256, 256, 0, stream>>>(weight, wBd);

  conv108_mfma_kernel<<<dim3(576, 2), 256, 0, stream>>>(xTbf, wB, b_off, b_mask,
                                                        zp, convA, convB);
  combine_softmax_kernel<<<BN / 256, 256, 0, stream>>>(convA, convB);
  deform_mfma_kernel<<<dim3(576, 2), 256, 0, stream>>>(xTbf, convA, wBd, out, p1);
  reduce_kernel<<<(BN * COUT_ / 4) / 256, 256, 0, stream>>>(out, p1, bias);
}

// Round 9
// 377.927 us; speedup vs baseline: 1.2046x; 1.0127x over previous
//
#include <hip/hip_runtime.h>
#include <hip/hip_bf16.h>
#include <math.h>

#define B_    4
#define CIN_  64
#define COUT_ 64
#define DD    8
#define HH    48
#define WW    48
#define HW2   (HH * WW)        // 2304
#define NN    (DD * HH * WW)   // 18432
#define BN    (B_ * NN)        // 73728
#define KK    27
#define OCT   108

typedef float f32x2 __attribute__((ext_vector_type(2)));
typedef float f32x4 __attribute__((ext_vector_type(4)));
typedef unsigned int u32x4 __attribute__((ext_vector_type(4)));
typedef __bf16 bf16x8 __attribute__((ext_vector_type(8)));
typedef __hip_bfloat16 bf16_t;

__device__ __forceinline__ float bflo(unsigned int u) {
  return __uint_as_float(u << 16);
}
__device__ __forceinline__ float bfhi(unsigned int u) {
  return __uint_as_float(u & 0xffff0000u);
}

// ---------------------------------------------------------------------------
__global__ void zp_init_kernel(bf16_t* __restrict__ zp)
{
  zp[threadIdx.x] = __float2bfloat16(0.f);
}

// ---------------------------------------------------------------------------
// Transpose x[b][c][n] -> xTbf[b][n][c] in bf16.
// ---------------------------------------------------------------------------
__global__ __launch_bounds__(256) void transpose_x_kernel(
    const float* __restrict__ x, bf16_t* __restrict__ xTbf)
{
  const int tid = threadIdx.x;
  const int n0  = blockIdx.x * 64;
  const int b   = blockIdx.y;
  __shared__ float tile[64][65];

  for (int i = tid; i < 4096; i += 256) {
    const int c  = i >> 6;
    const int nl = i & 63;
    tile[c][nl] = x[((size_t)(b * CIN_ + c)) * NN + n0 + nl];
  }
  __syncthreads();
  for (int i = tid; i < 4096; i += 256) {
    const int nl = i >> 6;
    const int c  = i & 63;
    xTbf[((size_t)(b * NN + n0 + nl)) * CIN_ + c] = __float2bfloat16(tile[c][nl]);
  }
}

// ---------------------------------------------------------------------------
// Conv weights wB[k][ch(112 pad)][cin] bf16 (offset+mask fused).
// ---------------------------------------------------------------------------
__global__ __launch_bounds__(256) void wb_build_kernel(
    const float* __restrict__ w_off, const float* __restrict__ w_mask,
    bf16_t* __restrict__ wB)
{
  const int o  = blockIdx.x * 256 + threadIdx.x;   // 27*112*64
  const int ci = o & 63;
  const int ch = (o >> 6) % 112;
  const int k  = o / (112 * 64);
  float v = 0.f;
  if (ch < 81)       v = w_off[((size_t)ch * CIN_ + ci) * KK + k];
  else if (ch < 108) v = w_mask[((size_t)(ch - 81) * CIN_ + ci) * KK + k];
  wB[o] = __float2bfloat16(v);
}

// ---------------------------------------------------------------------------
// Deform weights wBd[k][cout][cin] bf16.
// ---------------------------------------------------------------------------
__global__ __launch_bounds__(256) void wbd_build_kernel(
    const float* __restrict__ weight, bf16_t* __restrict__ wBd)
{
  const int o  = blockIdx.x * 256 + threadIdx.x;   // 110592
  const int ci = o & 63;
  const int co = (o >> 6) & 63;
  const int k  = o >> 12;
  wBd[o] = __float2bfloat16(weight[((size_t)co * CIN_ + ci) * KK + k]);
}

// ---------------------------------------------------------------------------
// Kernel 1: fused 108-ch 3x3x3 conv via MFMA (one wave = 32 pos x 112 ch),
// split-K over taps. Register-double-buffered A-fragments: tap k+1's loads
// issue before tap k's MFMA cluster. Full unroll (constexpr trip count).
// Output layout (k-major): conv*[k][b*NN+n][4] = {oz,oy,ox,mask-logit} fp32.
// ---------------------------------------------------------------------------
template<int K0, int K1, bool BIAS>
__device__ __forceinline__ void conv_impl(
    const bf16_t* __restrict__ xTbf, const bf16_t* __restrict__ wB,
    const float* __restrict__ b_off, const float* __restrict__ b_mask,
    const bf16_t* __restrict__ zp, float* __restrict__ target)
{
  const int bid  = (blockIdx.x % 8) * 72 + blockIdx.x / 8;  // XCD swizzle (576=8*72)
  const int tid  = threadIdx.x;
  const int wave = tid >> 6;
  const int lane = tid & 63;
  const int lg   = lane >> 4;
  const int lr   = lane & 15;

  const int gw = bid * 4 + wave;              // 0..2303
  const int b  = gw / 576;
  const int n0 = (gw % 576) * 32;

  int zj[2], yj[2], xj[2];
#pragma unroll
  for (int mf = 0; mf < 2; ++mf) {
    const int n   = n0 + 16 * mf + lr;
    const int z   = n / HW2;
    const int rem = n - z * HW2;
    const int y   = rem / WW;
    zj[mf] = z; yj[mf] = y; xj[mf] = rem - y * WW;
  }
  const bf16_t* xb = xTbf + (size_t)b * NN * CIN_;

  f32x4 acc[2][7];
#pragma unroll
  for (int mf = 0; mf < 2; ++mf)
#pragma unroll
    for (int nf = 0; nf < 7; ++nf) acc[mf][nf] = (f32x4){0.f, 0.f, 0.f, 0.f};

  // prologue: load A-fragments for tap K0
  bf16x8 aC[2][2];
  {
    const int kz = K0 / 9, kr = K0 - kz * 9, ky = kr / 3, kx = kr - ky * 3;
#pragma unroll
    for (int mf = 0; mf < 2; ++mf) {
      const int zz = zj[mf] + kz - 1;
      const int yy = yj[mf] + ky - 1;
      const int xx = xj[mf] + kx - 1;
      const bool v = ((unsigned)zz < (unsigned)DD) &
                     ((unsigned)yy < (unsigned)HH) &
                     ((unsigned)xx < (unsigned)WW);
      const bf16_t* ab = v ? (xb + (size_t)((zz * HH + yy) * WW + xx) * CIN_) : zp;
      aC[mf][0] = *(const bf16x8*)(ab + 8 * lg);
      aC[mf][1] = *(const bf16x8*)(ab + 32 + 8 * lg);
    }
  }

#pragma unroll
  for (int k = K0; k < K1; ++k) {
    // prefetch next tap's A-fragments (in flight during this tap's MFMAs)
    bf16x8 aN[2][2];
    if (k + 1 < K1) {
      const int k2 = k + 1;
      const int kz = k2 / 9, kr = k2 - kz * 9, ky = kr / 3, kx = kr - ky * 3;
#pragma unroll
      for (int mf = 0; mf < 2; ++mf) {
        const int zz = zj[mf] + kz - 1;
        const int yy = yj[mf] + ky - 1;
        const int xx = xj[mf] + kx - 1;
        const bool v = ((unsigned)zz < (unsigned)DD) &
                       ((unsigned)yy < (unsigned)HH) &
                       ((unsigned)xx < (unsigned)WW);
        const bf16_t* ab = v ? (xb + (size_t)((zz * HH + yy) * WW + xx) * CIN_) : zp;
        aN[mf][0] = *(const bf16x8*)(ab + 8 * lg);
        aN[mf][1] = *(const bf16x8*)(ab + 32 + 8 * lg);
      }
    }

    // batch this tap's B-loads, then the MFMA cluster
    const bf16_t* wk = wB + (size_t)k * (112 * 64) + lr * 64 + 8 * lg;
    bf16x8 bb0[7], bb1[7];
#pragma unroll
    for (int nf = 0; nf < 7; ++nf) {
      bb0[nf] = *(const bf16x8*)(wk + nf * 1024);
      bb1[nf] = *(const bf16x8*)(wk + nf * 1024 + 32);
    }
#pragma unroll
    for (int nf = 0; nf < 7; ++nf) {
      acc[0][nf] = __builtin_amdgcn_mfma_f32_16x16x32_bf16(aC[0][0], bb0[nf], acc[0][nf], 0, 0, 0);
      acc[1][nf] = __builtin_amdgcn_mfma_f32_16x16x32_bf16(aC[1][0], bb0[nf], acc[1][nf], 0, 0, 0);
      acc[0][nf] = __builtin_amdgcn_mfma_f32_16x16x32_bf16(aC[0][1], bb1[nf], acc[0][nf], 0, 0, 0);
      acc[1][nf] = __builtin_amdgcn_mfma_f32_16x16x32_bf16(aC[1][1], bb1[nf], acc[1][nf], 0, 0, 0);
    }
    if (k + 1 < K1) {
#pragma unroll
      for (int mf = 0; mf < 2; ++mf) {
        aC[mf][0] = aN[mf][0];
        aC[mf][1] = aN[mf][1];
      }
    }
  }

  // epilogue: optional bias + store into k-major [k][bn][4] layout.
#pragma unroll
  for (int nf = 0; nf < 7; ++nf) {
    const int ch = 16 * nf + lr;
    if (ch < 108) {
      const float bv = BIAS ? ((ch < 81) ? b_off[ch] : b_mask[ch - 81]) : 0.f;
      const int   kI = (ch < 81) ? (ch / 3) : (ch - 81);
      const int   d  = (ch < 81) ? (ch % 3) : 3;
#pragma unroll
      for (int mf = 0; mf < 2; ++mf)
#pragma unroll
        for (int r = 0; r < 4; ++r) {
          const int row = n0 + 16 * mf + 4 * lg + r;
          target[((size_t)kI * BN + (size_t)b * NN + row) * 4 + d] =
              acc[mf][nf][r] + bv;
        }
    }
  }
}

__global__ __launch_bounds__(256) void conv108_mfma_kernel(
    const bf16_t* __restrict__ xTbf, const bf16_t* __restrict__ wB,
    const float* __restrict__ b_off, const float* __restrict__ b_mask,
    const bf16_t* __restrict__ zp, float* __restrict__ convA,
    float* __restrict__ convB)
{
  if (blockIdx.y == 0) conv_impl<0, 14, true >(xTbf, wB, b_off, b_mask, zp, convA);
  else                 conv_impl<14, 27, false>(xTbf, wB, b_off, b_mask, zp, convB);
}

// ---------------------------------------------------------------------------
// Kernel 2: combine partials (convA += convB) and softmax the K=27 mask
// logits, all in one coalesced pass. One thread per position.
// ---------------------------------------------------------------------------
__global__ __launch_bounds__(256) void combine_softmax_kernel(
    float* __restrict__ convA, const float* __restrict__ convB)
{
  const int i = blockIdx.x * 256 + threadIdx.x;   // BN exact
  f32x4* pa = (f32x4*)convA + i;
  const f32x4* pb = (const f32x4*)convB + i;

  float lg[KK];
  float mx = -1e30f;
#pragma unroll
  for (int k = 0; k < KK; ++k) {
    f32x4 a = pa[(size_t)k * BN];
    const f32x4 b = pb[(size_t)k * BN];
    a.x += b.x; a.y += b.y; a.z += b.z; a.w += b.w;
    pa[(size_t)k * BN] = a;          // offsets final; .w = logit (rewritten below)
    lg[k] = a.w;
    mx = fmaxf(mx, a.w);
  }
  float s = 0.f;
#pragma unroll
  for (int k = 0; k < KK; ++k) { lg[k] = expf(lg[k] - mx); s += lg[k]; }
  const float inv = 1.f / s;
#pragma unroll
  for (int k = 0; k < KK; ++k)
    convA[((size_t)k * BN + i) * 4 + 3] = lg[k] * inv;
}

// ---------------------------------------------------------------------------
// Kernel 3: deformable gather (octet scheme) + MFMA tap-GEMM,
// split-K 2-way (grid.y: taps 0..13 -> out, 14..26 -> p1).
// This round: explicit load batching — om x4 hoisted, 8 corner loads per
// octet issued before the blend, 8 wk loads batched before the MFMA cluster,
// vectorized f32x4 epilogue stores.
// ---------------------------------------------------------------------------
__global__ __launch_bounds__(256) void deform_mfma_kernel(
    const bf16_t* __restrict__ xTbf, const float* __restrict__ convO,
    const bf16_t* __restrict__ wBd, float* __restrict__ out0,
    float* __restrict__ p1)
{
  const int bid  = (blockIdx.x % 8) * 72 + blockIdx.x / 8;   // XCD swizzle
  const int g    = blockIdx.y;
  const int k0   = g ? 14 : 0;
  const int kN   = g ? 13 : 14;
  float* target  = g ? p1 : out0;

  const int tid  = threadIdx.x;
  const int wid  = tid >> 6;
  const int lane = tid & 63;
  const int p8   = lane >> 3;     // position within octet
  const int q    = lane & 7;      // channel octet
  const int lr   = lane & 15;     // MFMA row/col
  const int lg   = lane >> 4;

  const int tile = bid * 4 + wid;           // 0..2303
  const int b    = tile / 576;
  const int rem  = tile % 576;
  const int z    = rem / 72;
  const int r2   = rem % 72;
  const int y0   = (r2 / 3) * 2;
  const int x0   = (r2 % 3) * 16;
  const int n0   = (z * HH + y0) * WW + x0;
  const size_t n0g = (size_t)b * NN + n0;

  const unsigned short* xq =
      (const unsigned short*)(xTbf + (size_t)b * NN * CIN_) + (q << 3);

  __shared__ __align__(16) unsigned short S[4][32][64];
  unsigned short* Sw  = &S[wid][0][0];
  unsigned int*   SwU = (unsigned int*)Sw;

  // per-lane constants for the 4 octets
  int   pOff[4];
  float pxb[4], pyb[4];
#pragma unroll
  for (int oct = 0; oct < 4; ++oct) {
    const int j  = oct * 8 + p8;
    const int jy = j >> 4;
    const int jx = j & 15;
    pOff[oct] = jy * WW + jx;                 // position offset in n
    pyb[oct]  = (float)(y0 + jy - 1);
    pxb[oct]  = (float)(x0 + jx - 1);
  }
  const float pzb = (float)(z - 1);

  f32x4 acc[2][4];
#pragma unroll
  for (int mf = 0; mf < 2; ++mf)
#pragma unroll
    for (int nf = 0; nf < 4; ++nf) acc[mf][nf] = (f32x4){0.f, 0.f, 0.f, 0.f};

#pragma unroll 2
  for (int t = 0; t < kN; ++t) {
    const int k  = k0 + t;
    const int kz = k / 9;
    const int kr = k - kz * 9;
    const int ky = kr / 3;
    const int kx = kr - ky * 3;
    const float kzf = (float)kz, kyf = (float)ky, kxf = (float)kx;

    const float* cbk = convO + ((size_t)k * BN + n0g) * 4;

    // hoisted om loads: 4 in flight
    f32x4 om4[4];
#pragma unroll
    for (int oct = 0; oct < 4; ++oct)
      om4[oct] = *(const f32x4*)(cbk + (size_t)pOff[oct] * 4);

    // ---- Phase A: gather 8 positions x 64 channels per octet ----
#pragma unroll
    for (int oct = 0; oct < 4; ++oct) {
      const int j = oct * 8 + p8;
      const f32x4 om = om4[oct];

      const float pz = pzb + kzf + om.x;
      const float py = pyb[oct] + kyf + om.y;
      const float px = pxb[oct] + kxf + om.z;
      const float m  = om.w;

      const float zf = floorf(pz); const float fz = pz - zf; const int z0 = (int)zf;
      const float yf = floorf(py); const float fy = py - yf; const int y0i = (int)yf;
      const float xf = floorf(px); const float fx = px - xf; const int xi0 = (int)xf;

      const float wz0 = ((unsigned)z0        < DD) ? (1.f - fz) : 0.f;
      const float wz1 = ((unsigned)(z0 + 1)  < DD) ? fz         : 0.f;
      const float wy0 = ((unsigned)y0i       < HH) ? (1.f - fy) : 0.f;
      const float wy1 = ((unsigned)(y0i + 1) < HH) ? fy         : 0.f;
      const float wx0 = ((unsigned)xi0       < WW) ? (1.f - fx) : 0.f;
      const float wx1 = ((unsigned)(xi0 + 1) < WW) ? fx         : 0.f;

      const int z0c = min(max(z0, 0),      DD - 1);
      const int z1c = min(max(z0 + 1, 0),  DD - 1);
      const int y0c = min(max(y0i, 0),     HH - 1);
      const int y1c = min(max(y0i + 1, 0), HH - 1);
      const int x0c = min(max(xi0, 0),     WW - 1);
      const int x1c = min(max(xi0 + 1, 0), WW - 1);

      const int r00 = (z0c * HH + y0c) * WW;
      const int r01 = (z0c * HH + y1c) * WW;
      const int r10 = (z1c * HH + y0c) * WW;
      const int r11 = (z1c * HH + y1c) * WW;

      const int rows[8] = {r00 + x0c, r00 + x1c, r01 + x0c, r01 + x1c,
                           r10 + x0c, r10 + x1c, r11 + x0c, r11 + x1c};
      const float w00 = wz0 * wy0, w01 = wz0 * wy1;
      const float w10 = wz1 * wy0, w11 = wz1 * wy1;
      const float wgt[8] = {w00 * wx0, w00 * wx1, w01 * wx0, w01 * wx1,
                            w10 * wx0, w10 * wx1, w11 * wx0, w11 * wx1};

      // issue all 8 corner loads, then blend (8-deep MLP)
      u32x4 cv[8];
#pragma unroll
      for (int c = 0; c < 8; ++c)
        cv[c] = *(const u32x4*)(xq + ((size_t)rows[c] << 6));

      f32x2 a01 = {0.f, 0.f}, a23 = {0.f, 0.f}, a45 = {0.f, 0.f}, a67 = {0.f, 0.f};
#pragma unroll
      for (int c = 0; c < 8; ++c) {
        const float w_ = wgt[c];
        a01 += (f32x2){bflo(cv[c].x), bfhi(cv[c].x)} * w_;
        a23 += (f32x2){bflo(cv[c].y), bfhi(cv[c].y)} * w_;
        a45 += (f32x2){bflo(cv[c].z), bfhi(cv[c].z)} * w_;
        a67 += (f32x2){bflo(cv[c].w), bfhi(cv[c].w)} * w_;
      }

      a01 *= m; a23 *= m; a45 *= m; a67 *= m;
      unsigned int d0, d1, d2, d3;
      asm("v_cvt_pk_bf16_f32 %0, %1, %2" : "=v"(d0) : "v"(a01.x), "v"(a01.y));
      asm("v_cvt_pk_bf16_f32 %0, %1, %2" : "=v"(d1) : "v"(a23.x), "v"(a23.y));
      asm("v_cvt_pk_bf16_f32 %0, %1, %2" : "=v"(d2) : "v"(a45.x), "v"(a45.y));
      asm("v_cvt_pk_bf16_f32 %0, %1, %2" : "=v"(d3) : "v"(a67.x), "v"(a67.y));
      const int slot = q ^ (j & 7);               // XOR-swizzle (T2)
      *(u32x4*)(SwU + j * 32 + slot * 4) = (u32x4){d0, d1, d2, d3};
    }

    // ---- Phase B: S[32x64] * W_k[64x64] via MFMA (loads batched) ----
    bf16x8 afr[2][2];
#pragma unroll
    for (int mf = 0; mf < 2; ++mf)
#pragma unroll
      for (int t2 = 0; t2 < 2; ++t2) {
        const int row  = 16 * mf + lr;
        const int slot = (t2 * 4 + lg) ^ (row & 7);
        afr[mf][t2] = *(const bf16x8*)(Sw + row * 64 + slot * 8);
      }
    const bf16_t* wk = wBd + (size_t)k * 4096 + lr * 64 + 8 * lg;
    bf16x8 wv0[4], wv1[4];
#pragma unroll
    for (int nf = 0; nf < 4; ++nf) {
      wv0[nf] = *(const bf16x8*)(wk + nf * 1024);
      wv1[nf] = *(const bf16x8*)(wk + nf * 1024 + 32);
    }
#pragma unroll
    for (int nf = 0; nf < 4; ++nf) {
      acc[0][nf] = __builtin_amdgcn_mfma_f32_16x16x32_bf16(afr[0][0], wv0[nf], acc[0][nf], 0, 0, 0);
      acc[1][nf] = __builtin_amdgcn_mfma_f32_16x16x32_bf16(afr[1][0], wv0[nf], acc[1][nf], 0, 0, 0);
      acc[0][nf] = __builtin_amdgcn_mfma_f32_16x16x32_bf16(afr[0][1], wv1[nf], acc[0][nf], 0, 0, 0);
      acc[1][nf] = __builtin_amdgcn_mfma_f32_16x16x32_bf16(afr[1][1], wv1[nf], acc[1][nf], 0, 0, 0);
    }
  }

  // epilogue (no bias; added in reduce). row=16mf+4lg+r -> n = n0+mf*WW+4lg+r,
  // col = cout = 16*nf+lr. r consecutive -> one f32x4 store per (nf,mf).
#pragma unroll
  for (int nf = 0; nf < 4; ++nf) {
    float* op = target + ((size_t)(b * COUT_ + 16 * nf + lr)) * NN + n0 + 4 * lg;
#pragma unroll
    for (int mf = 0; mf < 2; ++mf)
      *(f32x4*)(op + mf * WW) = acc[mf][nf];
  }
}

// ---------------------------------------------------------------------------
// Kernel 4: out += p1 + bias  (f32x4 vectorized)
// ---------------------------------------------------------------------------
__global__ __launch_bounds__(256) void reduce_kernel(
    float* __restrict__ out, const float* __restrict__ p1,
    const float* __restrict__ bias)
{
  const int i = blockIdx.x * 256 + threadIdx.x;   // BN*COUT/4 exact
  const int cout = (i / (NN / 4)) & 63;
  const f32x4 a = ((const f32x4*)out)[i];
  const f32x4 c = ((const f32x4*)p1)[i];
  const float bv = bias[cout];
  ((f32x4*)out)[i] = a + c + bv;
}

// ---------------------------------------------------------------------------
extern "C" void kernel_launch(void* const* d_in, const int* in_sizes, int n_in,
                              void* d_out, int out_size, void* d_ws, size_t ws_size,
                              hipStream_t stream)
{
  const float* x      = (const float*)d_in[0];
  const float* w_off  = (const float*)d_in[1];
  const float* b_off  = (const float*)d_in[2];
  const float* w_mask = (const float*)d_in[3];
  const float* b_mask = (const float*)d_in[4];
  const float* weight = (const float*)d_in[5];
  const float* bias   = (const float*)d_in[6];
  float* out = (float*)d_out;

  // Workspace (bytes):
  //   convA : 27*BN*4 fp32    = 31,850,496   @ 0
  //   xTbf  : BN*64 bf16      =  9,437,184   @ 31,850,496
  //   wB    : 27*112*64 bf16  =    387,072   @ 41,287,680
  //   wBd   : 27*64*64 bf16   =    221,184   @ 41,674,752
  //   zp    : 256             @ 41,895,936
  //   convB : 27*BN*4 fp32    = 31,850,496   @ 41,896,192
  //           (p1 aliases convB: convB is dead after combine_softmax)
  // total 73,746,688 B
  char* ws = (char*)d_ws;
  float*  convA = (float*)ws;
  bf16_t* xTbf  = (bf16_t*)(ws + 31850496);
  bf16_t* wB    = (bf16_t*)(ws + 41287680);
  bf16_t* wBd   = (bf16_t*)(ws + 41674752);
  bf16_t* zp    = (bf16_t*)(ws + 41895936);
  float*  convB = (float*)(ws + 41896192);
  float*  p1    = convB;   // alias (convB dead after combine_softmax)

  zp_init_kernel<<<1, 64, 0, stream>>>(zp);
  dim3 gtx(NN / 64, B_);
  transpose_x_kernel<<<gtx, 256, 0, stream>>>(x, xTbf);
  wb_build_kernel<<<(KK * 112 * 64) / 256, 256, 0, stream>>>(w_off, w_mask, wB);
  wbd_build_kernel<<<(KK * CIN_ * COUT_) / 256, 256, 0, stream>>>(weight, wBd);

  conv108_mfma_kernel<<<dim3(576, 2), 256, 0, stream>>>(xTbf, wB, b_off, b_mask,
                                                        zp, convA, convB);
  combine_softmax_kernel<<<BN / 256, 256, 0, stream>>>(convA, convB);
  deform_mfma_kernel<<<dim3(576, 2), 256, 0, stream>>>(xTbf, convA, wBd, out, p1);
  reduce_kernel<<<(BN * COUT_ / 4) / 256, 256, 0, stream>>>(out, p1, bias);
}